// Round 7
// baseline (29620.105 us; speedup 1.0000x reference)
//
#include <hip/hip_runtime.h>
#include <hip/hip_fp16.h>

#define B_   32
#define T_   1024
#define H_   1024
#define NL_  4
#define NBLK 256
#define NTHR 256

typedef _Float16 half8 __attribute__((ext_vector_type(8)));
typedef float    f32x4 __attribute__((ext_vector_type(4)));

// ---- grid barrier (R7): dense flags, wave-0 poll, all-wave acquire ----------
// Bisect rationale: R5/R6 failed with IDENTICAL absmax despite different sync
// protocols -> the regression is in their shared geometry/head rewrite, not
// sync. R7 keeps the ENTIRE R4-proven kernel and changes only this barrier:
//  - dense u32 flags (256 x 4B) instead of 128B-strided lines
//  - only wave 0 polls (4 coalesced loads/sweep vs 65K strided spinners in
//    R4 -- the poll flood suspected as R4's dominant 23.6us/step term)
//  - release store by tid0 (XCD L2 writeback before flag visible), acquire
//    fence by ALL threads after the closing barrier (each wave invalidates
//    before its own subsequent loads -- exactly R4's proven semantics).
__device__ __forceinline__ void gbar(unsigned* flags, unsigned ep) {
  __syncthreads();                       // drain vmem; all waves arrive
  if (threadIdx.x == 0)
    __hip_atomic_store(&flags[blockIdx.x], ep, __ATOMIC_RELEASE,
                       __HIP_MEMORY_SCOPE_AGENT);
  if (threadIdx.x < 64) {                // wave 0 only: coalesced poll
    const int ln = threadIdx.x;
    for (;;) {
      unsigned f0 = __hip_atomic_load(&flags[ln],       __ATOMIC_RELAXED, __HIP_MEMORY_SCOPE_AGENT);
      unsigned f1 = __hip_atomic_load(&flags[64 + ln],  __ATOMIC_RELAXED, __HIP_MEMORY_SCOPE_AGENT);
      unsigned f2 = __hip_atomic_load(&flags[128 + ln], __ATOMIC_RELAXED, __HIP_MEMORY_SCOPE_AGENT);
      unsigned f3 = __hip_atomic_load(&flags[192 + ln], __ATOMIC_RELAXED, __HIP_MEMORY_SCOPE_AGENT);
      if (__all(f0 >= ep && f1 >= ep && f2 >= ep && f3 >= ep)) break;
      __builtin_amdgcn_s_sleep(1);
    }
  }
  __syncthreads();                       // all waves wait for wave0's poll
  __builtin_amdgcn_fence(__ATOMIC_ACQUIRE, "agent");  // per-wave inv, then load
}

__device__ __forceinline__ half8 cvt8(const float* p) {
  float4 u = *(const float4*)p;
  float4 v = *(const float4*)(p + 4);
  half8 r;
  r[0]=(_Float16)u.x; r[1]=(_Float16)u.y; r[2]=(_Float16)u.z; r[3]=(_Float16)u.w;
  r[4]=(_Float16)v.x; r[5]=(_Float16)v.y; r[6]=(_Float16)v.z; r[7]=(_Float16)v.w;
  return r;
}

// Grid: 256 blocks = 4 layers x 64 col-blocks (16 hidden cols each), 256 thr.
// Layer-pipelined wavefront: layer l computes timestep t at step s = t + l;
// critical path = T+NL-1 = 1027 barriers. Weights pinned in VGPRs for the
// whole kernel. MFMA A/B fragments use the same (lane-group,j)->k formula, so
// the result is invariant to the exact hardware k mapping.
extern "C" __global__ void __launch_bounds__(NTHR)
rnn_persist(const float* __restrict__ x,  const float* __restrict__ Wi,
            const float* __restrict__ Wh, const float* __restrict__ bias,
            const float* __restrict__ fcW,const float* __restrict__ fcb,
            float* __restrict__ out, unsigned char* __restrict__ ws)
{
  __shared__ float red[8*256];   // [wave*2+mtile][col*16 + row]
  __shared__ float blds[16];

  unsigned* flags = (unsigned*)ws;                             // 256 x u32 dense
  _Float16* hbuf  = (_Float16*)(ws + 65536);                   // [NL][2][B_][H_] fp16 ring
  float*    hlast = (float*)(ws + 65536 + (size_t)NL_*2*B_*H_*2); // [B_][H_] fp32

  const int tid = threadIdx.x;
  const int bid = blockIdx.x;
  const int l   = bid >> 6;       // layer
  const int cb  = bid & 63;       // 16-col block
  const int wv  = tid >> 6;       // wave id
  const int ln  = tid & 63;
  const int lq  = ln & 15;        // A batch-row / B col / D col
  const int lg  = ln >> 4;        // k-group

  // ---- one-time: pin this block's weight slices in VGPRs (fragment order) ----
  half8 bfr[16];                  // [0..7] Wi k-tiles, [8..15] Wh k-tiles
  {
    const float* Wl  = Wi + (size_t)l*H_*H_;
    const float* Whl = Wh + (size_t)l*H_*H_;
    #pragma unroll
    for (int q = 0; q < 8; ++q) {
      const int kt = wv*8 + q;
      const float* s0 = Wl  + (size_t)(kt*32 + lg*8)*H_ + cb*16 + lq;
      const float* s1 = Whl + (size_t)(kt*32 + lg*8)*H_ + cb*16 + lq;
      half8 f0, f1;
      #pragma unroll
      for (int j = 0; j < 8; ++j) {
        f0[j] = (_Float16)s0[(size_t)j*H_];
        f1[j] = (_Float16)s1[(size_t)j*H_];
      }
      bfr[q]   = f0;
      bfr[8+q] = f1;
    }
  }
  if (tid < 16) blds[tid] = bias[l*H_ + cb*16 + tid];

  unsigned ep = 0;

  // ---- layer-pipelined recurrence: layer l handles t = s - l ----
  for (int s = 0; s < T_ + NL_ - 1; ++s) {
    const int t = s - l;
    if ((unsigned)t < (unsigned)T_) {
      f32x4 acc0 = {0.f,0.f,0.f,0.f};
      f32x4 acc1 = {0.f,0.f,0.f,0.f};

      if (l == 0) {  // input = x[:, t, :] fp32, convert on the fly
        const float* px = x + (size_t)lq*(T_*H_) + (size_t)t*H_ + lg*8;
        #pragma unroll
        for (int q = 0; q < 8; ++q) {
          const int kt = wv*8 + q;
          half8 a0 = cvt8(px + kt*32);
          half8 a1 = cvt8(px + (size_t)16*(T_*H_) + kt*32);
          acc0 = __builtin_amdgcn_mfma_f32_16x16x32_f16(a0, bfr[q], acc0, 0,0,0);
          acc1 = __builtin_amdgcn_mfma_f32_16x16x32_f16(a1, bfr[q], acc1, 0,0,0);
        }
      } else {       // input = previous layer's h at time t (fp16 ring)
        const _Float16* pi = hbuf + ((l-1)*2 + (t&1))*(B_*H_) + lq*H_ + lg*8;
        #pragma unroll
        for (int q = 0; q < 8; ++q) {
          const int kt = wv*8 + q;
          half8 a0 = *(const half8*)(pi + kt*32);
          half8 a1 = *(const half8*)(pi + 16*H_ + kt*32);
          acc0 = __builtin_amdgcn_mfma_f32_16x16x32_f16(a0, bfr[q], acc0, 0,0,0);
          acc1 = __builtin_amdgcn_mfma_f32_16x16x32_f16(a1, bfr[q], acc1, 0,0,0);
        }
      }
      if (t > 0) {   // recurrent term h_{t-1} @ Wh
        const _Float16* ph = hbuf + (l*2 + ((t-1)&1))*(B_*H_) + lq*H_ + lg*8;
        #pragma unroll
        for (int q = 0; q < 8; ++q) {
          const int kt = wv*8 + q;
          half8 a0 = *(const half8*)(ph + kt*32);
          half8 a1 = *(const half8*)(ph + 16*H_ + kt*32);
          acc0 = __builtin_amdgcn_mfma_f32_16x16x32_f16(a0, bfr[8+q], acc0, 0,0,0);
          acc1 = __builtin_amdgcn_mfma_f32_16x16x32_f16(a1, bfr[8+q], acc1, 0,0,0);
        }
      }

      // cross-wave K reduction via LDS. C/D layout (m89-verified):
      // col = lane&15, row = (lane>>4)*4 + i.
      *(f32x4*)(red + (wv*2+0)*256 + lq*16 + lg*4) = acc0;
      *(f32x4*)(red + (wv*2+1)*256 + lq*16 + lg*4) = acc1;
      __syncthreads();

      // epilogue map: col fastest across threads -> coalesced fp16 stores
      const int m    = tid >> 7;          // batch tile (rows 0-15 / 16-31)
      const int col  = tid & 15;          // hidden col within block
      const int row8 = (tid >> 4) & 7;    // rows row8 and row8+8
      const float* p0 = red + m*256 + col*16 + row8;
      float s0 = p0[0] + p0[512] + p0[1024] + p0[1536];
      float s1 = p0[8] + p0[520] + p0[1032] + p0[1544];
      const float bb = blds[col];
      const float h0 = tanhf(s0 + bb);
      const float h1 = tanhf(s1 + bb);
      const int b0 = m*16 + row8;
      const int hc = cb*16 + col;
      _Float16* ho = hbuf + (l*2 + (t&1))*(B_*H_);
      ho[(size_t)b0*H_ + hc]     = (_Float16)h0;
      ho[(size_t)(b0+8)*H_ + hc] = (_Float16)h1;
      if (l == NL_-1 && t == T_-1) {      // keep final h in fp32 for the head
        hlast[b0*H_ + hc]     = h0;
        hlast[(b0+8)*H_ + hc] = h1;
      }
    }
    ++ep;
    gbar(flags, ep);
  }

  // ---- dense head: out = hlast @ fcW + fcb, 4 cols per block ----
  if (tid < 128) {
    const int c = bid*4 + (tid & 3);
    const int b = tid >> 2;
    const float* hv = hlast + (size_t)b*H_;
    const float* wp = fcW + c;
    float a0=0.f, a1=0.f, a2=0.f, a3=0.f;
    for (int k = 0; k < H_; k += 4) {
      a0 += hv[k+0] * wp[(size_t)(k+0)*H_];
      a1 += hv[k+1] * wp[(size_t)(k+1)*H_];
      a2 += hv[k+2] * wp[(size_t)(k+2)*H_];
      a3 += hv[k+3] * wp[(size_t)(k+3)*H_];
    }
    out[(size_t)b*H_ + c] = fcb[c] + a0 + a1 + a2 + a3;
  }
}

extern "C" void kernel_launch(void* const* d_in, const int* in_sizes, int n_in,
                              void* d_out, int out_size, void* d_ws, size_t ws_size,
                              hipStream_t stream) {
  const float* x   = (const float*)d_in[0];
  const float* Wi  = (const float*)d_in[1];
  const float* Wh  = (const float*)d_in[2];
  const float* b   = (const float*)d_in[3];
  const float* fcW = (const float*)d_in[4];
  const float* fcb = (const float*)d_in[5];
  float* out = (float*)d_out;
  unsigned char* ws = (unsigned char*)d_ws;

  // flag region is poisoned each call -> zero it (captured in the graph)
  hipMemsetAsync(d_ws, 0, 65536, stream);

  void* args[] = { (void*)&x, (void*)&Wi, (void*)&Wh, (void*)&b,
                   (void*)&fcW, (void*)&fcb, (void*)&out, (void*)&ws };
  hipLaunchCooperativeKernel((const void*)rnn_persist, dim3(NBLK), dim3(NTHR),
                             args, 0, stream);
}

// Round 8
// 18442.674 us; speedup vs baseline: 1.6061x; 1.6061x over previous
//
#include <hip/hip_runtime.h>
#include <hip/hip_fp16.h>

#define B_   32
#define T_   1024
#define H_   1024
#define NL_  4
#define NBLK 256
#define NTHR 256

typedef _Float16 half8  __attribute__((ext_vector_type(8)));
typedef _Float16 half2t __attribute__((ext_vector_type(2)));
typedef float    f32x4  __attribute__((ext_vector_type(4)));

// ---- fence-free h path (R8 single-variable experiment) ----------------------
// R2/R4/R7 all cost 23-29us/step across three different poll structures ->
// polling was never the bottleneck; the per-step agent release/acquire fences
// (XCD-L2 writeback + cache-wide invalidate + full L2 refill from L3 every
// step) are. R8 removes ALL fences: h ring + hlast move exclusively through
// relaxed agent-scope atomic loads/stores (sc-bit ops that bypass L1/L2 to
// the L3 coherence point -> nothing is ever stale, nothing is invalidated;
// x/weights stay plain-cached and L2-resident). Ordering: __syncthreads
// drains vmcnt (h atomic-stores retired at L3) before tid0's flag store;
// consumer h-loads issue only after the poll observed the flag, so they
// serialize after the producer's stores at L3. This is a clean bisect: the
// ONLY change vs the passing R7 kernel is the h-path protocol. If it fails
// like R5 (absmax 2.4), fence-free is convicted and R5/R6's geometry is
// exonerated; if it passes, the maintenance cost is gone.
__device__ __forceinline__ unsigned long long a_load_u64(const void* p) {
  return __hip_atomic_load((unsigned long long*)p, __ATOMIC_RELAXED,
                           __HIP_MEMORY_SCOPE_AGENT);
}
__device__ __forceinline__ half8 a_load_h8(const _Float16* p) {
  struct Q { unsigned long long a, b; } s;
  s.a = a_load_u64(p);
  s.b = a_load_u64(p + 4);
  return __builtin_bit_cast(half8, s);
}
__device__ __forceinline__ void a_store_u32(void* p, unsigned v) {
  __hip_atomic_store((unsigned*)p, v, __ATOMIC_RELAXED,
                     __HIP_MEMORY_SCOPE_AGENT);
}

// Barrier: dense flags, wave-0 poll, NO fences (see above).
__device__ __forceinline__ void gbar(unsigned* flags, unsigned ep) {
  __syncthreads();                       // drain vmcnt: h stores retired at L3
  if (threadIdx.x == 0)
    __hip_atomic_store(&flags[blockIdx.x], ep, __ATOMIC_RELAXED,
                       __HIP_MEMORY_SCOPE_AGENT);
  if (threadIdx.x < 64) {                // wave 0 only: coalesced poll
    const int ln = threadIdx.x;
    for (;;) {
      unsigned f0 = __hip_atomic_load(&flags[ln],       __ATOMIC_RELAXED, __HIP_MEMORY_SCOPE_AGENT);
      unsigned f1 = __hip_atomic_load(&flags[64 + ln],  __ATOMIC_RELAXED, __HIP_MEMORY_SCOPE_AGENT);
      unsigned f2 = __hip_atomic_load(&flags[128 + ln], __ATOMIC_RELAXED, __HIP_MEMORY_SCOPE_AGENT);
      unsigned f3 = __hip_atomic_load(&flags[192 + ln], __ATOMIC_RELAXED, __HIP_MEMORY_SCOPE_AGENT);
      if (__all(f0 >= ep && f1 >= ep && f2 >= ep && f3 >= ep)) break;
      __builtin_amdgcn_s_sleep(1);
    }
  }
  __syncthreads();                       // waves 1-3 wait on wave0's poll
  asm volatile("" ::: "memory");         // no compiler reordering across
}

__device__ __forceinline__ half8 cvt8(const float* p) {
  float4 u = *(const float4*)p;
  float4 v = *(const float4*)(p + 4);
  half8 r;
  r[0]=(_Float16)u.x; r[1]=(_Float16)u.y; r[2]=(_Float16)u.z; r[3]=(_Float16)u.w;
  r[4]=(_Float16)v.x; r[5]=(_Float16)v.y; r[6]=(_Float16)v.z; r[7]=(_Float16)v.w;
  return r;
}

// Grid: 256 blocks = 4 layers x 64 col-blocks (16 hidden cols each), 256 thr.
// Layer-pipelined wavefront: layer l computes timestep t at step s = t + l;
// critical path = T+NL-1 = 1027 barriers. Weights pinned in VGPRs. MFMA A/B
// fragments use the same (lane-group,j)->k formula -> k-permutation invariant.
extern "C" __global__ void __launch_bounds__(NTHR)
rnn_persist(const float* __restrict__ x,  const float* __restrict__ Wi,
            const float* __restrict__ Wh, const float* __restrict__ bias,
            const float* __restrict__ fcW,const float* __restrict__ fcb,
            float* __restrict__ out, unsigned char* __restrict__ ws)
{
  __shared__ float red[8*256];   // [wave*2+mtile][col*16 + row]
  __shared__ float blds[16];

  unsigned* flags = (unsigned*)ws;                             // 256 x u32 dense
  _Float16* hbuf  = (_Float16*)(ws + 65536);                   // [NL][2][B_][H_] fp16 ring
  float*    hlast = (float*)(ws + 65536 + (size_t)NL_*2*B_*H_*2); // [B_][H_] fp32

  const int tid = threadIdx.x;
  const int bid = blockIdx.x;
  const int l   = bid >> 6;       // layer
  const int cb  = bid & 63;       // 16-col block
  const int wv  = tid >> 6;       // wave id
  const int ln  = tid & 63;
  const int lq  = ln & 15;        // A batch-row / B col / D col
  const int lg  = ln >> 4;        // k-group

  // ---- one-time: pin this block's weight slices in VGPRs (fragment order) ----
  half8 bfr[16];                  // [0..7] Wi k-tiles, [8..15] Wh k-tiles
  {
    const float* Wl  = Wi + (size_t)l*H_*H_;
    const float* Whl = Wh + (size_t)l*H_*H_;
    #pragma unroll
    for (int q = 0; q < 8; ++q) {
      const int kt = wv*8 + q;
      const float* s0 = Wl  + (size_t)(kt*32 + lg*8)*H_ + cb*16 + lq;
      const float* s1 = Whl + (size_t)(kt*32 + lg*8)*H_ + cb*16 + lq;
      half8 f0, f1;
      #pragma unroll
      for (int j = 0; j < 8; ++j) {
        f0[j] = (_Float16)s0[(size_t)j*H_];
        f1[j] = (_Float16)s1[(size_t)j*H_];
      }
      bfr[q]   = f0;
      bfr[8+q] = f1;
    }
  }
  if (tid < 16) blds[tid] = bias[l*H_ + cb*16 + tid];

  unsigned ep = 0;

  // ---- layer-pipelined recurrence: layer l handles t = s - l ----
  for (int s = 0; s < T_ + NL_ - 1; ++s) {
    const int t = s - l;
    if ((unsigned)t < (unsigned)T_) {
      f32x4 acc0 = {0.f,0.f,0.f,0.f};
      f32x4 acc1 = {0.f,0.f,0.f,0.f};

      if (l == 0) {  // input = x[:, t, :] fp32 (plain cached loads, read-only)
        const float* px = x + (size_t)lq*(T_*H_) + (size_t)t*H_ + lg*8;
        #pragma unroll
        for (int q = 0; q < 8; ++q) {
          const int kt = wv*8 + q;
          half8 a0 = cvt8(px + kt*32);
          half8 a1 = cvt8(px + (size_t)16*(T_*H_) + kt*32);
          acc0 = __builtin_amdgcn_mfma_f32_16x16x32_f16(a0, bfr[q], acc0, 0,0,0);
          acc1 = __builtin_amdgcn_mfma_f32_16x16x32_f16(a1, bfr[q], acc1, 0,0,0);
        }
      } else {       // input = previous layer's h (coherent bypass loads)
        const _Float16* pi = hbuf + ((l-1)*2 + (t&1))*(B_*H_) + lq*H_ + lg*8;
        #pragma unroll
        for (int q = 0; q < 8; ++q) {
          const int kt = wv*8 + q;
          half8 a0 = a_load_h8(pi + kt*32);
          half8 a1 = a_load_h8(pi + 16*H_ + kt*32);
          acc0 = __builtin_amdgcn_mfma_f32_16x16x32_f16(a0, bfr[q], acc0, 0,0,0);
          acc1 = __builtin_amdgcn_mfma_f32_16x16x32_f16(a1, bfr[q], acc1, 0,0,0);
        }
      }
      if (t > 0) {   // recurrent term h_{t-1} @ Wh (coherent bypass loads)
        const _Float16* ph = hbuf + (l*2 + ((t-1)&1))*(B_*H_) + lq*H_ + lg*8;
        #pragma unroll
        for (int q = 0; q < 8; ++q) {
          const int kt = wv*8 + q;
          half8 a0 = a_load_h8(ph + kt*32);
          half8 a1 = a_load_h8(ph + 16*H_ + kt*32);
          acc0 = __builtin_amdgcn_mfma_f32_16x16x32_f16(a0, bfr[8+q], acc0, 0,0,0);
          acc1 = __builtin_amdgcn_mfma_f32_16x16x32_f16(a1, bfr[8+q], acc1, 0,0,0);
        }
      }

      // cross-wave K reduction via LDS. C/D layout (m89-verified):
      // col = lane&15, row = (lane>>4)*4 + i.
      *(f32x4*)(red + (wv*2+0)*256 + lq*16 + lg*4) = acc0;
      *(f32x4*)(red + (wv*2+1)*256 + lq*16 + lg*4) = acc1;
      __syncthreads();

      // epilogue: thread -> (row, col-pair); one packed u32 bypass store
      const int r   = tid >> 3;           // batch row 0..31
      const int cp  = tid & 7;            // col pair 0..7
      const int c0  = cp*2, c1 = c0 + 1;
      const int m   = r >> 4;
      const int r15 = r & 15;
      const float* p0 = red + m*256 + r15;
      float s0 = p0[c0*16] + p0[c0*16+512] + p0[c0*16+1024] + p0[c0*16+1536];
      float s1 = p0[c1*16] + p0[c1*16+512] + p0[c1*16+1024] + p0[c1*16+1536];
      const float h0 = tanhf(s0 + blds[c0]);
      const float h1 = tanhf(s1 + blds[c1]);
      half2t v2 = { (_Float16)h0, (_Float16)h1 };
      _Float16* ho = hbuf + (l*2 + (t&1))*(B_*H_) + (size_t)r*H_ + cb*16 + c0;
      a_store_u32(ho, __builtin_bit_cast(unsigned, v2));
      if (l == NL_-1 && t == T_-1) {      // final h in fp32 for the head
        a_store_u32(&hlast[(size_t)r*H_ + cb*16 + c0], __builtin_bit_cast(unsigned, h0));
        a_store_u32(&hlast[(size_t)r*H_ + cb*16 + c1], __builtin_bit_cast(unsigned, h1));
      }
    }
    ++ep;
    gbar(flags, ep);
  }

  // ---- dense head: out = hlast @ fcW + fcb, 4 cols per block ----
  if (tid < 128) {
    const int c = bid*4 + (tid & 3);
    const int b = tid >> 2;
    const float* hv = hlast + (size_t)b*H_;
    const float* wp = fcW + c;
    float a0 = 0.f, a1 = 0.f;
    for (int k = 0; k < H_; k += 2) {
      float2 f = __builtin_bit_cast(float2, a_load_u64(hv + k));
      a0 += f.x * wp[(size_t)k*H_];
      a1 += f.y * wp[(size_t)(k+1)*H_];
    }
    out[(size_t)b*H_ + c] = fcb[c] + a0 + a1;
  }
}

extern "C" void kernel_launch(void* const* d_in, const int* in_sizes, int n_in,
                              void* d_out, int out_size, void* d_ws, size_t ws_size,
                              hipStream_t stream) {
  const float* x   = (const float*)d_in[0];
  const float* Wi  = (const float*)d_in[1];
  const float* Wh  = (const float*)d_in[2];
  const float* b   = (const float*)d_in[3];
  const float* fcW = (const float*)d_in[4];
  const float* fcb = (const float*)d_in[5];
  float* out = (float*)d_out;
  unsigned char* ws = (unsigned char*)d_ws;

  // flag region is poisoned each call -> zero it (captured in the graph)
  hipMemsetAsync(d_ws, 0, 65536, stream);

  void* args[] = { (void*)&x, (void*)&Wi, (void*)&Wh, (void*)&b,
                   (void*)&fcW, (void*)&fcb, (void*)&out, (void*)&ws };
  hipLaunchCooperativeKernel((const void*)rnn_persist, dim3(NBLK), dim3(NTHR),
                             args, 0, stream);
}

// Round 9
// 15052.408 us; speedup vs baseline: 1.9678x; 1.2252x over previous
//
#include <hip/hip_runtime.h>
#include <hip/hip_fp16.h>

#define B_    32
#define T_    1024
#define H_    1024
#define NL_   4
#define NBLK  256
#define NTHR  256
#define DEPTH 4       // h-ring slots per layer (slack absorbs jitter)

typedef _Float16 half8  __attribute__((ext_vector_type(8)));
typedef _Float16 half2t __attribute__((ext_vector_type(2)));
typedef float    f32x4  __attribute__((ext_vector_type(4)));

// ---- R8-proven bypass data path (relaxed agent atomics, no fences) ----------
// h ring + hlast move exclusively through relaxed agent-scope atomics (sc-bit
// ops serviced at the L3 coherence point; nothing stale, no cache-maintenance
// per step). Ordering: __syncthreads drains vmcnt (h stores retired) before
// the flag store; consumer h-loads issue only after the poll observed the
// flag. x/weights stay plain-cached (read-only).
__device__ __forceinline__ unsigned a_load_u32(const unsigned* p) {
  return __hip_atomic_load(p, __ATOMIC_RELAXED, __HIP_MEMORY_SCOPE_AGENT);
}
__device__ __forceinline__ unsigned long long a_load_u64(const void* p) {
  return __hip_atomic_load((const unsigned long long*)p, __ATOMIC_RELAXED,
                           __HIP_MEMORY_SCOPE_AGENT);
}
__device__ __forceinline__ half8 a_load_h8(const _Float16* p) {
  struct Q { unsigned long long a, b; } s;
  s.a = a_load_u64(p);
  s.b = a_load_u64(p + 4);
  return __builtin_bit_cast(half8, s);
}
__device__ __forceinline__ void a_store_u32(void* p, unsigned v) {
  __hip_atomic_store((unsigned*)p, v, __ATOMIC_RELAXED,
                     __HIP_MEMORY_SCOPE_AGENT);
}

__device__ __forceinline__ half8 cvt8(const float* p) {
  float4 u = *(const float4*)p;
  float4 v = *(const float4*)(p + 4);
  half8 r;
  r[0]=(_Float16)u.x; r[1]=(_Float16)u.y; r[2]=(_Float16)u.z; r[3]=(_Float16)u.w;
  r[4]=(_Float16)v.x; r[5]=(_Float16)v.y; r[6]=(_Float16)v.z; r[7]=(_Float16)v.w;
  return r;
}

// R9: NO global barrier. Per-block progress flags (flag = timesteps done) and
// a depth-4 h ring give an elastic pipeline: layer l at t waits only on
//   prev layer >= t+1  (input h ready)          [checked before input read]
//   next layer >= t-3  (ring slot free to write)[checked before write]
//   own  layer >= t    (h_{t-1} complete)       [checked before recurrent]
// R8 measured 17.9us/step under a global barrier vs ~5us justified chain ->
// theory: max-of-256-blocks jitter accrued every step. Decoupling absorbs
// jitter in ring slack; layer 0 runs ahead so x latency leaves the critical
// path. Deadlock-free: marked graph with capacity-4 buffers, least-advanced
// layer always enabled.
extern "C" __global__ void __launch_bounds__(NTHR)
rnn_persist(const float* __restrict__ x,  const float* __restrict__ Wi,
            const float* __restrict__ Wh, const float* __restrict__ bias,
            const float* __restrict__ fcW,const float* __restrict__ fcb,
            float* __restrict__ out, unsigned char* __restrict__ ws)
{
  __shared__ float red[8*256];   // [wave*2+mtile][col*16 + row]
  __shared__ float blds[16];

  unsigned* flags = (unsigned*)ws;                              // [NL][64] u32
  _Float16* hbuf  = (_Float16*)(ws + 65536);                    // [NL][DEPTH][B_][H_] fp16
  float*    hlast = (float*)(ws + 65536 + (size_t)NL_*DEPTH*B_*H_*2); // [B_][H_] fp32

  const int tid = threadIdx.x;
  const int bid = blockIdx.x;
  const int l   = bid >> 6;       // layer
  const int cb  = bid & 63;       // 16-col block
  const int wv  = tid >> 6;       // wave id
  const int ln  = tid & 63;
  const int lq  = ln & 15;        // A batch-row / B col / D col
  const int lg  = ln >> 4;        // k-group

  // ---- one-time: pin this block's weight slices in VGPRs (fragment order) ----
  // MFMA A/B fragments share one (lane-group,j)->k formula -> result is
  // invariant to the hardware's exact k mapping (k-permutation trick).
  half8 bfr[16];                  // [0..7] Wi k-tiles, [8..15] Wh k-tiles
  {
    const float* Wl  = Wi + (size_t)l*H_*H_;
    const float* Whl = Wh + (size_t)l*H_*H_;
    #pragma unroll
    for (int q = 0; q < 8; ++q) {
      const int kt = wv*8 + q;
      const float* s0 = Wl  + (size_t)(kt*32 + lg*8)*H_ + cb*16 + lq;
      const float* s1 = Whl + (size_t)(kt*32 + lg*8)*H_ + cb*16 + lq;
      half8 f0, f1;
      #pragma unroll
      for (int j = 0; j < 8; ++j) {
        f0[j] = (_Float16)s0[(size_t)j*H_];
        f1[j] = (_Float16)s1[(size_t)j*H_];
      }
      bfr[q]   = f0;
      bfr[8+q] = f1;
    }
  }
  if (tid < 16) blds[tid] = bias[l*H_ + cb*16 + tid];

  // ---- elastic time loop: every block runs all T_ timesteps of its layer ----
  for (int t = 0; t < T_; ++t) {
    // wait #1: producer ready (l>0) + ring back-pressure (l<NL-1)
    if (tid < 64) {
      for (;;) {
        bool ok = true;
        if (l > 0)
          ok &= (int)a_load_u32(&flags[(l-1)*64 + ln]) >= t + 1;
        if (l < NL_-1)
          ok &= (int)a_load_u32(&flags[(l+1)*64 + ln]) >= t - (DEPTH-1);
        if (__all(ok)) break;
        __builtin_amdgcn_s_sleep(1);
      }
    }
    __syncthreads();
    asm volatile("" ::: "memory");

    f32x4 acc0 = {0.f,0.f,0.f,0.f};
    f32x4 acc1 = {0.f,0.f,0.f,0.f};

    // input-projection half (off the own-layer critical loop)
    if (l == 0) {  // x[:, t, :] fp32, plain cached loads
      const float* px = x + (size_t)lq*(T_*H_) + (size_t)t*H_ + lg*8;
      #pragma unroll
      for (int q = 0; q < 8; ++q) {
        const int kt = wv*8 + q;
        half8 a0 = cvt8(px + kt*32);
        half8 a1 = cvt8(px + (size_t)16*(T_*H_) + kt*32);
        acc0 = __builtin_amdgcn_mfma_f32_16x16x32_f16(a0, bfr[q], acc0, 0,0,0);
        acc1 = __builtin_amdgcn_mfma_f32_16x16x32_f16(a1, bfr[q], acc1, 0,0,0);
      }
    } else {       // previous layer's h(t), ring slot (l-1, t&3)
      const _Float16* pi = hbuf + ((size_t)((l-1)*DEPTH + (t&3)))*(B_*H_) + lq*H_ + lg*8;
      #pragma unroll
      for (int q = 0; q < 8; ++q) {
        const int kt = wv*8 + q;
        half8 a0 = a_load_h8(pi + kt*32);
        half8 a1 = a_load_h8(pi + 16*H_ + kt*32);
        acc0 = __builtin_amdgcn_mfma_f32_16x16x32_f16(a0, bfr[q], acc0, 0,0,0);
        acc1 = __builtin_amdgcn_mfma_f32_16x16x32_f16(a1, bfr[q], acc1, 0,0,0);
      }
    }

    // wait #2: own layer finished t-1 (trivial at t=0)
    if (tid < 64) {
      for (;;) {
        bool ok = (int)a_load_u32(&flags[l*64 + ln]) >= t;
        if (__all(ok)) break;
        __builtin_amdgcn_s_sleep(1);
      }
    }
    __syncthreads();
    asm volatile("" ::: "memory");

    if (t > 0) {   // recurrent term h_{t-1} @ Wh, ring slot (l, (t-1)&3)
      const _Float16* ph = hbuf + ((size_t)(l*DEPTH + ((t-1)&3)))*(B_*H_) + lq*H_ + lg*8;
      #pragma unroll
      for (int q = 0; q < 8; ++q) {
        const int kt = wv*8 + q;
        half8 a0 = a_load_h8(ph + kt*32);
        half8 a1 = a_load_h8(ph + 16*H_ + kt*32);
        acc0 = __builtin_amdgcn_mfma_f32_16x16x32_f16(a0, bfr[8+q], acc0, 0,0,0);
        acc1 = __builtin_amdgcn_mfma_f32_16x16x32_f16(a1, bfr[8+q], acc1, 0,0,0);
      }
    }

    // cross-wave K reduction via LDS. C/D layout (m89-verified):
    // col = lane&15, row = (lane>>4)*4 + i.
    *(f32x4*)(red + (wv*2+0)*256 + lq*16 + lg*4) = acc0;
    *(f32x4*)(red + (wv*2+1)*256 + lq*16 + lg*4) = acc1;
    __syncthreads();

    // epilogue: thread -> (row, col-pair); one packed u32 bypass store
    const int r   = tid >> 3;           // batch row 0..31
    const int cp  = tid & 7;            // col pair 0..7
    const int c0  = cp*2, c1 = c0 + 1;
    const int m   = r >> 4;
    const int r15 = r & 15;
    const float* p0 = red + m*256 + r15;
    float s0 = p0[c0*16] + p0[c0*16+512] + p0[c0*16+1024] + p0[c0*16+1536];
    float s1 = p0[c1*16] + p0[c1*16+512] + p0[c1*16+1024] + p0[c1*16+1536];
    const float h0 = tanhf(s0 + blds[c0]);
    const float h1 = tanhf(s1 + blds[c1]);
    half2t v2 = { (_Float16)h0, (_Float16)h1 };
    _Float16* ho = hbuf + ((size_t)(l*DEPTH + (t&3)))*(B_*H_) + (size_t)r*H_ + cb*16 + c0;
    a_store_u32(ho, __builtin_bit_cast(unsigned, v2));
    if (l == NL_-1 && t == T_-1) {      // final h in fp32 for the head
      a_store_u32(&hlast[(size_t)r*H_ + cb*16 + c0], __builtin_bit_cast(unsigned, h0));
      a_store_u32(&hlast[(size_t)r*H_ + cb*16 + c1], __builtin_bit_cast(unsigned, h1));
    }

    __syncthreads();                    // drain stores (vmcnt(0) before barrier)
    if (tid == 0)
      a_store_u32(&flags[l*64 + cb], (unsigned)(t + 1));
  }

  // ---- wait until layer 3 fully done, then dense head ----
  if (tid < 64) {
    for (;;) {
      bool ok = (int)a_load_u32(&flags[(NL_-1)*64 + ln]) >= T_;
      if (__all(ok)) break;
      __builtin_amdgcn_s_sleep(1);
    }
  }
  __syncthreads();
  asm volatile("" ::: "memory");

  // out = hlast @ fcW + fcb, 4 cols per block (R8-proven scalar head)
  if (tid < 128) {
    const int c = bid*4 + (tid & 3);
    const int b = tid >> 2;
    const float* hv = hlast + (size_t)b*H_;
    const float* wp = fcW + c;
    float a0 = 0.f, a1 = 0.f;
    for (int k = 0; k < H_; k += 2) {
      float2 f = __builtin_bit_cast(float2, a_load_u64(hv + k));
      a0 += f.x * wp[(size_t)k*H_];
      a1 += f.y * wp[(size_t)(k+1)*H_];
    }
    out[(size_t)b*H_ + c] = fcb[c] + a0 + a1;
  }
}

extern "C" void kernel_launch(void* const* d_in, const int* in_sizes, int n_in,
                              void* d_out, int out_size, void* d_ws, size_t ws_size,
                              hipStream_t stream) {
  const float* x   = (const float*)d_in[0];
  const float* Wi  = (const float*)d_in[1];
  const float* Wh  = (const float*)d_in[2];
  const float* b   = (const float*)d_in[3];
  const float* fcW = (const float*)d_in[4];
  const float* fcb = (const float*)d_in[5];
  float* out = (float*)d_out;
  unsigned char* ws = (unsigned char*)d_ws;

  // flag region is poisoned each call -> zero it (captured in the graph)
  hipMemsetAsync(d_ws, 0, 65536, stream);

  void* args[] = { (void*)&x, (void*)&Wi, (void*)&Wh, (void*)&b,
                   (void*)&fcW, (void*)&fcb, (void*)&out, (void*)&ws };
  hipLaunchCooperativeKernel((const void*)rnn_persist, dim3(NBLK), dim3(NTHR),
                             args, 0, stream);
}